// Round 4
// baseline (230.195 us; speedup 1.0000x reference)
//
#include <hip/hip_runtime.h>
#include <math.h>

#define T_SEQ 2048
#define CDIM  1024
#define HEADS 16
#define DHEAD 64
#define BATCH 2
#define M_ROWS 4096
#define QSCALE 0.18033688011112042f  // 0.125 * log2(e)

typedef unsigned short u16;
typedef unsigned int u32;
typedef __attribute__((ext_vector_type(8))) short bf16x8;
typedef __attribute__((ext_vector_type(4))) float f32x4;
typedef __attribute__((ext_vector_type(16))) float f32x16;

__device__ inline u16 f2bf(float f) {
    u32 u = __builtin_bit_cast(u32, f);
    u32 r = (u + 0x7fffu + ((u >> 16) & 1u)) >> 16;  // RNE
    return (u16)r;
}

__device__ inline u32 cvtpk(float lo, float hi) {
    u32 r;
    asm("v_cvt_pk_bf16_f32 %0, %1, %2" : "=v"(r) : "v"(lo), "v"(hi));
    return r;
}

// swap: x.hi-lanes <-> y.lo-lanes  (v_permlane32_swap_b32, gfx950)
__device__ inline void permswap(u32& x, u32& y) {
    asm volatile("v_permlane32_swap_b32 %0, %1" : "+v"(x), "+v"(y));
}

__device__ inline float fexp2(float x) {
#if __has_builtin(__builtin_amdgcn_exp2f)
    return __builtin_amdgcn_exp2f(x);
#else
    float r; asm("v_exp_f32 %0, %1" : "=v"(r) : "v"(x)); return r;
#endif
}

__device__ inline void gload16(const void* g, void* l) {
    __builtin_amdgcn_global_load_lds(
        (const __attribute__((address_space(1))) void*)g,
        (__attribute__((address_space(3))) void*)l, 16, 0, 0);
}

// ---------------------------------------------------------------------------
// RoPE cos/sin table [T][32]
// ---------------------------------------------------------------------------
__global__ void rope_table_kernel(float* __restrict__ cosT, float* __restrict__ sinT) {
    int idx = blockIdx.x * blockDim.x + threadIdx.x;
    if (idx >= T_SEQ * 32) return;
    int t = idx >> 5;
    int i = idx & 31;
    float expo = (2.0f * (float)i) / 64.0f;
    float inv = powf(10000.0f, -expo);
    float a = (float)t * inv;
    cosT[idx] = cosf(a);
    sinT[idx] = sinf(a);
}

// ---------------------------------------------------------------------------
// fp32 -> bf16 elementwise (8 elems/thread)
// ---------------------------------------------------------------------------
__global__ __launch_bounds__(256)
void conv_bf16(const float* __restrict__ in, u16* __restrict__ out, int n8) {
    int i = blockIdx.x * blockDim.x + threadIdx.x;
    if (i >= n8) return;
    const float4* p = (const float4*)(in + (size_t)i * 8);
    float4 a = p[0], b = p[1];
    uint4 o;
    o.x = (u32)f2bf(a.x) | ((u32)f2bf(a.y) << 16);
    o.y = (u32)f2bf(a.z) | ((u32)f2bf(a.w) << 16);
    o.z = (u32)f2bf(b.x) | ((u32)f2bf(b.y) << 16);
    o.w = (u32)f2bf(b.z) | ((u32)f2bf(b.w) << 16);
    *(uint4*)(out + (size_t)i * 8) = o;
}

// ---------------------------------------------------------------------------
// fp32 [K][N] -> bf16 [N][K] (weight transpose+convert), 64x64 tiles
// ---------------------------------------------------------------------------
__global__ __launch_bounds__(256)
void convT64(const float* __restrict__ in, u16* __restrict__ out, int K, int N) {
    __shared__ float Ls[64][65];
    const int tid = threadIdx.x;
    const int k0 = blockIdx.y << 6, n0 = blockIdx.x << 6;
    const int r0 = tid >> 4, c4 = (tid & 15) << 2;
#pragma unroll
    for (int p = 0; p < 4; p++) {
        int r = r0 + (p << 4);
        float4 v = *(const float4*)&in[(size_t)(k0 + r) * N + n0 + c4];
        Ls[r][c4 + 0] = v.x; Ls[r][c4 + 1] = v.y;
        Ls[r][c4 + 2] = v.z; Ls[r][c4 + 3] = v.w;
    }
    __syncthreads();
    const int n = tid >> 2, kq = (tid & 3) << 4;
    u32 pk[8];
#pragma unroll
    for (int j = 0; j < 8; j++) {
        float lo = Ls[kq + 2 * j][n], hi = Ls[kq + 2 * j + 1][n];
        pk[j] = (u32)f2bf(lo) | ((u32)f2bf(hi) << 16);
    }
    u32* dst = (u32*)&out[(size_t)(n0 + n) * K + k0 + kq];
    ((uint4*)dst)[0] = make_uint4(pk[0], pk[1], pk[2], pk[3]);
    ((uint4*)dst)[1] = make_uint4(pk[4], pk[5], pk[6], pk[7]);
}

// ---------------------------------------------------------------------------
// bf16 V [bh][2048][64] -> Vt [bh][64][2048], 64x64 tiles
// ---------------------------------------------------------------------------
__global__ __launch_bounds__(256)
void transposeV(const u16* __restrict__ in, u16* __restrict__ out) {
    __shared__ u16 Ls[64][72];
    const int tid = threadIdx.x;
    const int bh = blockIdx.y;
    const int t0 = blockIdx.x << 6;
    const u16* src = in + ((size_t)bh << 17) + ((size_t)t0 << 6);
#pragma unroll
    for (int p = 0; p < 2; p++) {
        int L = tid + (p << 8);
        int t = L >> 3, c = L & 7;
        uint4 v = *(const uint4*)&src[(size_t)t * 64 + (c << 3)];
        *(uint4*)&Ls[t][c << 3] = v;
    }
    __syncthreads();
    const int d = tid >> 2, tq = (tid & 3) << 4;
    u32 pk[8];
#pragma unroll
    for (int j = 0; j < 8; j++) {
        u16 lo = Ls[tq + 2 * j][d], hi = Ls[tq + 2 * j + 1][d];
        pk[j] = (u32)lo | ((u32)hi << 16);
    }
    u16* dst = out + ((size_t)bh << 17) + ((size_t)d << 11) + t0 + tq;
    ((uint4*)dst)[0] = make_uint4(pk[0], pk[1], pk[2], pk[3]);
    ((uint4*)dst)[1] = make_uint4(pk[4], pk[5], pk[6], pk[7]);
}

// ---------------------------------------------------------------------------
// bf16 MFMA GEMM, 128x128 tile, BK=32, dbl-buffered LDS + counted vmcnt.
// EPI=0: RoPE on q,k (+QSCALE on q); scatter Q/K/V bf16. EPI=1: +bias fp32.
// ---------------------------------------------------------------------------
template <int EPI>
__global__ __launch_bounds__(256)
void gemm_bf16(const u16* __restrict__ A, const u16* __restrict__ Bt,
               int N, int K,
               const float* __restrict__ bias, float* __restrict__ outF,
               u16* __restrict__ qOut, u16* __restrict__ kOut, u16* __restrict__ vOut,
               const float* __restrict__ cosT, const float* __restrict__ sinT) {
    __shared__ u16 Alds[2][128 * 32];
    __shared__ u16 Blds[2][128 * 32];
    const int tid = threadIdx.x;
    const int lane = tid & 63;
    const int w = tid >> 6;
    const int wr = w >> 1, wc = w & 1;
    const int g = lane >> 4, l15 = lane & 15;
    const int m0 = blockIdx.y * 128, n0 = blockIdx.x * 128;

    f32x4 acc[4][4];
#pragma unroll
    for (int m = 0; m < 4; m++)
#pragma unroll
        for (int n = 0; n < 4; n++)
#pragma unroll
            for (int e = 0; e < 4; e++) acc[m][n][e] = 0.f;

    int aoff[4], boff[4];
#pragma unroll
    for (int m = 0; m < 4; m++) {
        aoff[m] = ((wr << 6) + (m << 4) + l15) * 64 + (g << 4);
        boff[m] = ((wc << 6) + (m << 4) + l15) * 64 + (g << 4);
    }
    const int rowA0 = tid >> 2, kk0 = (tid & 3) << 3;

#define GSTAGE(BUF, K0)                                                          \
    {                                                                            \
        _Pragma("unroll") for (int pq = 0; pq < 2; pq++) {                       \
            int L = tid + (pq << 8);                                             \
            int row = rowA0 + (pq << 6);                                         \
            gload16(A + (size_t)(m0 + row) * K + (K0) + kk0, &Alds[BUF][0] + L * 8); \
            gload16(Bt + (size_t)(n0 + row) * K + (K0) + kk0, &Blds[BUF][0] + L * 8); \
        }                                                                        \
    }

    GSTAGE(0, 0);
    const int nt = K >> 5;
    int cur = 0;
    for (int t = 0; t < nt; t++) {
        if (t + 1 < nt) {
            GSTAGE(cur ^ 1, ((t + 1) << 5));
            asm volatile("s_waitcnt vmcnt(4)" ::: "memory");
        } else {
            asm volatile("s_waitcnt vmcnt(0)" ::: "memory");
        }
        __builtin_amdgcn_s_barrier();
        asm volatile("" ::: "memory");
        bf16x8 af[4], bfr[4];
#pragma unroll
        for (int m = 0; m < 4; m++) af[m] = *(const bf16x8*)((const char*)&Alds[cur][0] + aoff[m]);
#pragma unroll
        for (int n = 0; n < 4; n++) bfr[n] = *(const bf16x8*)((const char*)&Blds[cur][0] + boff[n]);
#pragma unroll
        for (int m = 0; m < 4; m++)
#pragma unroll
            for (int n = 0; n < 4; n++)
                acc[m][n] = __builtin_amdgcn_mfma_f32_16x16x32_bf16(af[m], bfr[n], acc[m][n], 0, 0, 0);
        asm volatile("" ::: "memory");
        __builtin_amdgcn_s_barrier();
        cur ^= 1;
    }
#undef GSTAGE

    if (EPI == 0) {
        const int sec = n0 >> 10;  // uniform per block
#pragma unroll
        for (int m = 0; m < 4; m++) {
#pragma unroll
            for (int j = 0; j < 4; j++) {
                int t = m0 + (wr << 6) + (m << 4) + (g << 2) + j;
                int b = t >> 11, tt = t & 2047;
#pragma unroll
                for (int n = 0; n < 4; n++) {
                    int cc = (n0 + (wc << 6) + (n << 4) + l15) & 1023;
                    int h = cc >> 6, d = cc & 63;
                    float val = acc[m][n][j];
                    float o = val;
                    if (sec < 2) {
                        float partner = __shfl_xor(val, 1);
                        int i0 = d >> 1;
                        float c = cosT[tt * 32 + i0], s = sinT[tt * 32 + i0];
                        o = ((d & 1) == 0) ? (val * c - partner * s)
                                           : (partner * s + val * c);
                        if (sec == 0) o *= QSCALE;
                    }
                    size_t off = (((size_t)((b * 16 + h) * 2048 + tt)) << 6) + d;
                    u16* dst = (sec == 0) ? qOut : ((sec == 1) ? kOut : vOut);
                    dst[off] = f2bf(o);
                }
            }
        }
    } else {
#pragma unroll
        for (int m = 0; m < 4; m++) {
#pragma unroll
            for (int j = 0; j < 4; j++) {
                int t = m0 + (wr << 6) + (m << 4) + (g << 2) + j;
#pragma unroll
                for (int n = 0; n < 4; n++) {
                    int col = n0 + (wc << 6) + (n << 4) + l15;
                    outF[(size_t)t * N + col] = acc[m][n][j] + bias[col];
                }
            }
        }
    }
}

// ---------------------------------------------------------------------------
// Flash attention, swapped-operand 32x32 MFMA.
// Block = 2 waves (128 thr); wave w owns 32 q-rows of a 64-row tile; tiles
// paired (p, 31-p). S^T = mfma(K, Q): lane = q-row, kv in regs. Softmax
// lane-local (1 shfl_xor(32) per reduce). P^T assembled in-register via
// cvt_pk_bf16 + permlane32_swap. O^T = mfma(V^T, P^T): lane = q-row again.
// ---------------------------------------------------------------------------
__device__ __forceinline__ void kv_stage2(const u16* Kb, const u16* Vtb,
                                          u16* Kl, u16* Vl, int tid, int k0) {
#pragma unroll
    for (int pp = 0; pp < 4; pp++) {
        int L = tid + (pp << 7);  // 0..511 chunks of 16B
        int row = L >> 3, c = L & 7;
        int cg = (c ^ (row & 7)) << 3;  // swizzled source column (elems)
        gload16(Kb + (((size_t)(k0 + row)) << 6) + cg, Kl + L * 8);
        gload16(Vtb + ((size_t)row << 11) + k0 + cg, Vl + L * 8);
    }
}

template <int NS>
__device__ __forceinline__ void attn_step32(
    const bf16x8 (&qf)[4], f32x16 (&O)[2], float& MR, float& LR,
    const char* Kl, const char* Vl, const int (&foff)[2][4],
    int lim, bool diag) {
    // S^T = K * Q  (per subtile s: 32 kv x 32 q)
    f32x16 st[NS];
#pragma unroll
    for (int s = 0; s < NS; s++) {
#pragma unroll
        for (int e = 0; e < 16; e++) st[s][e] = 0.f;
#pragma unroll
        for (int ks = 0; ks < 4; ks++) {
            bf16x8 kf = *(const bf16x8*)(Kl + foff[s][ks]);
            st[s] = __builtin_amdgcn_mfma_f32_32x32x16_bf16(kf, qf[ks], st[s], 0, 0, 0);
        }
    }
    if (diag) {  // triangle mask on last subtile: kvloc > l31 - 4*hl
#pragma unroll
        for (int r = 0; r < 16; r++) {
            const int kvloc = (r & 3) + 8 * (r >> 2);
            if (kvloc > lim) st[NS - 1][r] = -1e30f;
        }
    }
    // row max: in-lane tree + one cross-half swap
    float t8[8];
#pragma unroll
    for (int r = 0; r < 8; r++) {
        float a = fmaxf(st[0][r], st[0][r + 8]);
        if (NS == 2) a = fmaxf(a, fmaxf(st[1][r], st[1][r + 8]));
        t8[r] = a;
    }
    float m = fmaxf(fmaxf(fmaxf(t8[0], t8[4]), fmaxf(t8[1], t8[5])),
                    fmaxf(fmaxf(t8[2], t8[6]), fmaxf(t8[3], t8[7])));
    m = fmaxf(m, __shfl_xor(m, 32));
    float mn = fmaxf(MR, m);
    if (__ballot(m - MR > 10.f)) {  // defer-max
        float al = fexp2(MR - mn);
        MR = mn;
        LR *= al;
#pragma unroll
        for (int e = 0; e < 16; e++) { O[0][e] *= al; O[1][e] *= al; }
    }
    // P = exp2(S - MR) in place; 4-way interleaved sum tree
    float s0 = 0.f, s1 = 0.f, s2 = 0.f, s3 = 0.f;
#pragma unroll
    for (int s = 0; s < NS; s++)
#pragma unroll
        for (int r = 0; r < 16; r++) {
            float pv = fexp2(st[s][r] - MR);
            st[s][r] = pv;
            if ((r & 3) == 0) s0 += pv;
            else if ((r & 3) == 1) s1 += pv;
            else if ((r & 3) == 2) s2 += pv;
            else s3 += pv;
        }
    float sum = (s0 + s1) + (s2 + s3);
    sum += __shfl_xor(sum, 32);
    LR += sum;
    // P^T B-frags via cvt_pk + permlane32_swap; O^T += V^T * P^T
#pragma unroll
    for (int ks = 0; ks < 2 * NS; ks++) {
        const int sT = ks >> 1, b1 = (ks & 1) << 3;
        u32 a = cvtpk(st[sT][b1 + 0], st[sT][b1 + 1]);
        u32 b = cvtpk(st[sT][b1 + 2], st[sT][b1 + 3]);
        u32 c = cvtpk(st[sT][b1 + 4], st[sT][b1 + 5]);
        u32 d = cvtpk(st[sT][b1 + 6], st[sT][b1 + 7]);
        permswap(a, c);  // a -> word0, c -> word2
        permswap(b, d);  // b -> word1, d -> word3
        bf16x8 pf = __builtin_bit_cast(bf16x8, make_uint4(a, b, c, d));
#pragma unroll
        for (int t2 = 0; t2 < 2; t2++) {
            bf16x8 vf = *(const bf16x8*)(Vl + foff[t2][ks]);
            O[t2] = __builtin_amdgcn_mfma_f32_32x32x16_bf16(vf, pf, O[t2], 0, 0, 0);
        }
    }
}

__device__ __forceinline__ void attn_store32(
    const f32x16 (&O)[2], float LR, u16* __restrict__ Yg,
    int b, int hd, int q, int hl) {
    float inv = 1.0f / LR;
    size_t rowoff = (((size_t)(b * 2048 + q)) << 10) + (hd << 6);
#pragma unroll
    for (int t2 = 0; t2 < 2; t2++)
#pragma unroll
        for (int rg = 0; rg < 4; rg++) {
            int d0 = (rg << 3) + (hl << 2) + (t2 << 5);
            u32 lo = cvtpk(O[t2][4 * rg + 0] * inv, O[t2][4 * rg + 1] * inv);
            u32 hi = cvtpk(O[t2][4 * rg + 2] * inv, O[t2][4 * rg + 3] * inv);
            *(uint2*)&Yg[rowoff + d0] = make_uint2(lo, hi);
        }
}

__global__ __launch_bounds__(128)
void attn_mfma(const u16* __restrict__ Qg, const u16* __restrict__ Kg,
               const u16* __restrict__ Vtg, u16* __restrict__ Yg) {
    __shared__ u16 Ks[2][64 * 64];
    __shared__ u16 Vts[2][64 * 64];

    const int tid = threadIdx.x;
    const int lane = tid & 63;
    const int w = tid >> 6;           // 0,1
    const int l31 = lane & 31, hl = lane >> 5;
    const int p = blockIdx.x;         // 0..15
    const int bh = blockIdx.y;
    const int b = bh >> 4, hd = bh & 15;
    const int qtA = p, qtB = 31 - p;
    const int lim = l31 - (hl << 2);

    const u16* Qb = Qg + ((size_t)bh << 17);
    const u16* Kb = Kg + ((size_t)bh << 17);
    const u16* Vtb = Vtg + ((size_t)bh << 17);

    // fragment byte offsets into K/V LDS (shared form; s = kv-subtile or d-tile)
    int foff[2][4];
#pragma unroll
    for (int s = 0; s < 2; s++)
#pragma unroll
        for (int ks = 0; ks < 4; ks++) {
            int row = (s << 5) + l31;
            foff[s][ks] = row * 128 + (((hl + (ks << 1)) ^ (row & 7)) << 4);
        }

    // Q B-frags, both phases, direct global->register
    const int qrA = (qtA << 6) + (w << 5) + l31;
    const int qrB = (qtB << 6) + (w << 5) + l31;
    bf16x8 qfA[4], qfB[4];
#pragma unroll
    for (int ks = 0; ks < 4; ks++) {
        int co = (hl << 3) + (ks << 4);
        qfA[ks] = *(const bf16x8*)(Qb + (((size_t)qrA) << 6) + co);
        qfB[ks] = *(const bf16x8*)(Qb + (((size_t)qrB) << 6) + co);
    }

    kv_stage2(Kb, Vtb, &Ks[0][0], &Vts[0][0], tid, 0);
    int cur = 0;

    f32x16 O[2];
    float MR, LR;

    // ---- Phase A: q-tile qtA ----
#pragma unroll
    for (int e = 0; e < 16; e++) { O[0][e] = 0.f; O[1][e] = 0.f; }
    MR = -1e30f; LR = 0.f;
    for (int kt = 0; kt <= qtA; kt++) {
        int nk0 = (kt < qtA) ? ((kt + 1) << 6) : 0;  // last iter: phase-B kv0
        kv_stage2(Kb, Vtb, &Ks[cur ^ 1][0], &Vts[cur ^ 1][0], tid, nk0);
        asm volatile("s_waitcnt vmcnt(8)" ::: "memory");
        __builtin_amdgcn_s_barrier();
        asm volatile("" ::: "memory");
        if (kt == qtA) {
            if (w == 0)
                attn_step32<1>(qfA, O, MR, LR, (const char*)&Ks[cur][0],
                               (const char*)&Vts[cur][0], foff, lim, true);
            else
                attn_step32<2>(qfA, O, MR, LR, (const char*)&Ks[cur][0],
                               (const char*)&Vts[cur][0], foff, lim, true);
        } else {
            attn_step32<2>(qfA, O, MR, LR, (const char*)&Ks[cur][0],
                           (const char*)&Vts[cur][0], foff, lim, false);
        }
        asm volatile("" ::: "memory");
        __builtin_amdgcn_s_barrier();
        cur ^= 1;
    }
    attn_store32(O, LR, Yg, b, hd, qrA, hl);

    // ---- Phase B: q-tile qtB ----
#pragma unroll
    for (int e = 0; e < 16; e++) { O[0][e] = 0.f; O[1][e] = 0.f; }
    MR = -1e30f; LR = 0.f;
    for (int kt = 0; kt <= qtB; kt++) {
        if (kt < qtB) {
            kv_stage2(Kb, Vtb, &Ks[cur ^ 1][0], &Vts[cur ^ 1][0], tid, (kt + 1) << 6);
            asm volatile("s_waitcnt vmcnt(8)" ::: "memory");
        } else {
            asm volatile("s_waitcnt vmcnt(0)" ::: "memory");
        }
        __builtin_amdgcn_s_barrier();
        asm volatile("" ::: "memory");
        if (kt == qtB) {
            if (w == 0)
                attn_step32<1>(qfB, O, MR, LR, (const char*)&Ks[cur][0],
                               (const char*)&Vts[cur][0], foff, lim, true);
            else
                attn_step32<2>(qfB, O, MR, LR, (const char*)&Ks[cur][0],
                               (const char*)&Vts[cur][0], foff, lim, true);
        } else {
            attn_step32<2>(qfB, O, MR, LR, (const char*)&Ks[cur][0],
                           (const char*)&Vts[cur][0], foff, lim, false);
        }
        asm volatile("" ::: "memory");
        __builtin_amdgcn_s_barrier();
        cur ^= 1;
    }
    attn_store32(O, LR, Yg, b, hd, qrB, hl);
}

// ---------------------------------------------------------------------------
extern "C" void kernel_launch(void* const* d_in, const int* in_sizes, int n_in,
                              void* d_out, int out_size, void* d_ws, size_t ws_size,
                              hipStream_t stream) {
    const float* x      = (const float*)d_in[0];
    const float* w_qkv  = (const float*)d_in[1];
    const float* w_proj = (const float*)d_in[2];
    const float* b_proj = (const float*)d_in[3];
    float* out = (float*)d_out;

    const size_t SZ = (size_t)M_ROWS * CDIM;
    char* ws = (char*)d_ws;
    u16* xb     = (u16*)ws;                ws += SZ * 2;
    u16* wqkvT  = (u16*)ws;                ws += (size_t)3 * CDIM * CDIM * 2;
    u16* wprojT = (u16*)ws;                ws += (size_t)CDIM * CDIM * 2;
    u16* Qb     = (u16*)ws;                ws += SZ * 2;
    u16* Kb     = (u16*)ws;                ws += SZ * 2;
    u16* Vb     = (u16*)ws;                ws += SZ * 2;
    u16* Vt     = (u16*)ws;                ws += SZ * 2;
    u16* Yb     = (u16*)ws;                ws += SZ * 2;
    float* cosT = (float*)ws;              ws += (size_t)T_SEQ * 32 * 4;
    float* sinT = (float*)ws;              ws += (size_t)T_SEQ * 32 * 4;

    rope_table_kernel<<<dim3(256), dim3(256), 0, stream>>>(cosT, sinT);
    conv_bf16<<<dim3(2048), dim3(256), 0, stream>>>(x, xb, (int)(SZ / 8));
    convT64<<<dim3(48, 16), dim3(256), 0, stream>>>(w_qkv, wqkvT, CDIM, 3 * CDIM);
    convT64<<<dim3(16, 16), dim3(256), 0, stream>>>(w_proj, wprojT, CDIM, CDIM);

    gemm_bf16<0><<<dim3(24, 32), dim3(256), 0, stream>>>(
        xb, wqkvT, 3 * CDIM, CDIM, nullptr, nullptr, Qb, Kb, Vb, cosT, sinT);

    transposeV<<<dim3(32, 32), dim3(256), 0, stream>>>(Vb, Vt);

    attn_mfma<<<dim3(16, 32), dim3(128), 0, stream>>>(Qb, Kb, Vt, Yb);

    gemm_bf16<1><<<dim3(8, 32), dim3(256), 0, stream>>>(
        Yb, wprojT, CDIM, CDIM, b_proj, out, nullptr, nullptr, nullptr, nullptr, nullptr);
}

// Round 5
// 213.201 us; speedup vs baseline: 1.0797x; 1.0797x over previous
//
#include <hip/hip_runtime.h>
#include <math.h>

#define T_SEQ 2048
#define CDIM  1024
#define HEADS 16
#define DHEAD 64
#define BATCH 2
#define M_ROWS 4096
#define QSCALE 0.18033688011112042f  // 0.125 * log2(e)

typedef unsigned short u16;
typedef unsigned int u32;
typedef __attribute__((ext_vector_type(8))) short bf16x8;
typedef __attribute__((ext_vector_type(4))) float f32x4;
typedef __attribute__((ext_vector_type(16))) float f32x16;

__device__ inline u16 f2bf(float f) {
    u32 u = __builtin_bit_cast(u32, f);
    u32 r = (u + 0x7fffu + ((u >> 16) & 1u)) >> 16;  // RNE
    return (u16)r;
}

__device__ inline u32 cvtpk(float lo, float hi) {
    u32 r;
    asm("v_cvt_pk_bf16_f32 %0, %1, %2" : "=v"(r) : "v"(lo), "v"(hi));
    return r;
}

// swap: x.hi-lanes <-> y.lo-lanes  (v_permlane32_swap_b32, gfx950)
__device__ inline void permswap(u32& x, u32& y) {
    asm volatile("v_permlane32_swap_b32 %0, %1" : "+v"(x), "+v"(y));
}

__device__ inline float fexp2(float x) {
#if __has_builtin(__builtin_amdgcn_exp2f)
    return __builtin_amdgcn_exp2f(x);
#else
    float r; asm("v_exp_f32 %0, %1" : "=v"(r) : "v"(x)); return r;
#endif
}

__device__ inline void gload16(const void* g, void* l) {
    __builtin_amdgcn_global_load_lds(
        (const __attribute__((address_space(1))) void*)g,
        (__attribute__((address_space(3))) void*)l, 16, 0, 0);
}

// ---------------------------------------------------------------------------
// RoPE cos/sin table [T][32]
// ---------------------------------------------------------------------------
__global__ void rope_table_kernel(float* __restrict__ cosT, float* __restrict__ sinT) {
    int idx = blockIdx.x * blockDim.x + threadIdx.x;
    if (idx >= T_SEQ * 32) return;
    int t = idx >> 5;
    int i = idx & 31;
    float expo = (2.0f * (float)i) / 64.0f;
    float inv = powf(10000.0f, -expo);
    float a = (float)t * inv;
    cosT[idx] = cosf(a);
    sinT[idx] = sinf(a);
}

// ---------------------------------------------------------------------------
// fp32 -> bf16 elementwise (8 elems/thread)
// ---------------------------------------------------------------------------
__global__ __launch_bounds__(256)
void conv_bf16(const float* __restrict__ in, u16* __restrict__ out, int n8) {
    int i = blockIdx.x * blockDim.x + threadIdx.x;
    if (i >= n8) return;
    const float4* p = (const float4*)(in + (size_t)i * 8);
    float4 a = p[0], b = p[1];
    uint4 o;
    o.x = (u32)f2bf(a.x) | ((u32)f2bf(a.y) << 16);
    o.y = (u32)f2bf(a.z) | ((u32)f2bf(a.w) << 16);
    o.z = (u32)f2bf(b.x) | ((u32)f2bf(b.y) << 16);
    o.w = (u32)f2bf(b.z) | ((u32)f2bf(b.w) << 16);
    *(uint4*)(out + (size_t)i * 8) = o;
}

// ---------------------------------------------------------------------------
// fp32 [K][N] -> bf16 [N][K] (weight transpose+convert), 64x64 tiles
// ---------------------------------------------------------------------------
__global__ __launch_bounds__(256)
void convT64(const float* __restrict__ in, u16* __restrict__ out, int K, int N) {
    __shared__ float Ls[64][65];
    const int tid = threadIdx.x;
    const int k0 = blockIdx.y << 6, n0 = blockIdx.x << 6;
    const int r0 = tid >> 4, c4 = (tid & 15) << 2;
#pragma unroll
    for (int p = 0; p < 4; p++) {
        int r = r0 + (p << 4);
        float4 v = *(const float4*)&in[(size_t)(k0 + r) * N + n0 + c4];
        Ls[r][c4 + 0] = v.x; Ls[r][c4 + 1] = v.y;
        Ls[r][c4 + 2] = v.z; Ls[r][c4 + 3] = v.w;
    }
    __syncthreads();
    const int n = tid >> 2, kq = (tid & 3) << 4;
    u32 pk[8];
#pragma unroll
    for (int j = 0; j < 8; j++) {
        float lo = Ls[kq + 2 * j][n], hi = Ls[kq + 2 * j + 1][n];
        pk[j] = (u32)f2bf(lo) | ((u32)f2bf(hi) << 16);
    }
    u32* dst = (u32*)&out[(size_t)(n0 + n) * K + k0 + kq];
    ((uint4*)dst)[0] = make_uint4(pk[0], pk[1], pk[2], pk[3]);
    ((uint4*)dst)[1] = make_uint4(pk[4], pk[5], pk[6], pk[7]);
}

// ---------------------------------------------------------------------------
// bf16 V [bh][2048][64] -> Vt [bh][64][2048], 64x64 tiles
// ---------------------------------------------------------------------------
__global__ __launch_bounds__(256)
void transposeV(const u16* __restrict__ in, u16* __restrict__ out) {
    __shared__ u16 Ls[64][72];
    const int tid = threadIdx.x;
    const int bh = blockIdx.y;
    const int t0 = blockIdx.x << 6;
    const u16* src = in + ((size_t)bh << 17) + ((size_t)t0 << 6);
#pragma unroll
    for (int p = 0; p < 2; p++) {
        int L = tid + (p << 8);
        int t = L >> 3, c = L & 7;
        uint4 v = *(const uint4*)&src[(size_t)t * 64 + (c << 3)];
        *(uint4*)&Ls[t][c << 3] = v;
    }
    __syncthreads();
    const int d = tid >> 2, tq = (tid & 3) << 4;
    u32 pk[8];
#pragma unroll
    for (int j = 0; j < 8; j++) {
        u16 lo = Ls[tq + 2 * j][d], hi = Ls[tq + 2 * j + 1][d];
        pk[j] = (u32)lo | ((u32)hi << 16);
    }
    u16* dst = out + ((size_t)bh << 17) + ((size_t)d << 11) + t0 + tq;
    ((uint4*)dst)[0] = make_uint4(pk[0], pk[1], pk[2], pk[3]);
    ((uint4*)dst)[1] = make_uint4(pk[4], pk[5], pk[6], pk[7]);
}

// ---------------------------------------------------------------------------
// bf16 MFMA GEMM, 128x128 tile, BK=32, dbl-buffered LDS + counted vmcnt.
// EPI=0: RoPE on q,k (+QSCALE on q); scatter Q/K/V bf16. EPI=1: +bias fp32.
// ---------------------------------------------------------------------------
template <int EPI>
__global__ __launch_bounds__(256)
void gemm_bf16(const u16* __restrict__ A, const u16* __restrict__ Bt,
               int N, int K,
               const float* __restrict__ bias, float* __restrict__ outF,
               u16* __restrict__ qOut, u16* __restrict__ kOut, u16* __restrict__ vOut,
               const float* __restrict__ cosT, const float* __restrict__ sinT) {
    __shared__ u16 Alds[2][128 * 32];
    __shared__ u16 Blds[2][128 * 32];
    const int tid = threadIdx.x;
    const int lane = tid & 63;
    const int w = tid >> 6;
    const int wr = w >> 1, wc = w & 1;
    const int g = lane >> 4, l15 = lane & 15;
    const int m0 = blockIdx.y * 128, n0 = blockIdx.x * 128;

    f32x4 acc[4][4];
#pragma unroll
    for (int m = 0; m < 4; m++)
#pragma unroll
        for (int n = 0; n < 4; n++)
#pragma unroll
            for (int e = 0; e < 4; e++) acc[m][n][e] = 0.f;

    int aoff[4], boff[4];
#pragma unroll
    for (int m = 0; m < 4; m++) {
        aoff[m] = ((wr << 6) + (m << 4) + l15) * 64 + (g << 4);
        boff[m] = ((wc << 6) + (m << 4) + l15) * 64 + (g << 4);
    }
    const int rowA0 = tid >> 2, kk0 = (tid & 3) << 3;

#define GSTAGE(BUF, K0)                                                          \
    {                                                                            \
        _Pragma("unroll") for (int pq = 0; pq < 2; pq++) {                       \
            int L = tid + (pq << 8);                                             \
            int row = rowA0 + (pq << 6);                                         \
            gload16(A + (size_t)(m0 + row) * K + (K0) + kk0, &Alds[BUF][0] + L * 8); \
            gload16(Bt + (size_t)(n0 + row) * K + (K0) + kk0, &Blds[BUF][0] + L * 8); \
        }                                                                        \
    }

    GSTAGE(0, 0);
    const int nt = K >> 5;
    int cur = 0;
    for (int t = 0; t < nt; t++) {
        if (t + 1 < nt) {
            GSTAGE(cur ^ 1, ((t + 1) << 5));
            asm volatile("s_waitcnt vmcnt(4)" ::: "memory");
        } else {
            asm volatile("s_waitcnt vmcnt(0)" ::: "memory");
        }
        __builtin_amdgcn_s_barrier();
        asm volatile("" ::: "memory");
        bf16x8 af[4], bfr[4];
#pragma unroll
        for (int m = 0; m < 4; m++) af[m] = *(const bf16x8*)((const char*)&Alds[cur][0] + aoff[m]);
#pragma unroll
        for (int n = 0; n < 4; n++) bfr[n] = *(const bf16x8*)((const char*)&Blds[cur][0] + boff[n]);
#pragma unroll
        for (int m = 0; m < 4; m++)
#pragma unroll
            for (int n = 0; n < 4; n++)
                acc[m][n] = __builtin_amdgcn_mfma_f32_16x16x32_bf16(af[m], bfr[n], acc[m][n], 0, 0, 0);
        asm volatile("" ::: "memory");
        __builtin_amdgcn_s_barrier();
        cur ^= 1;
    }
#undef GSTAGE

    if (EPI == 0) {
        const int sec = n0 >> 10;  // uniform per block
#pragma unroll
        for (int m = 0; m < 4; m++) {
#pragma unroll
            for (int j = 0; j < 4; j++) {
                int t = m0 + (wr << 6) + (m << 4) + (g << 2) + j;
                int b = t >> 11, tt = t & 2047;
#pragma unroll
                for (int n = 0; n < 4; n++) {
                    int cc = (n0 + (wc << 6) + (n << 4) + l15) & 1023;
                    int h = cc >> 6, d = cc & 63;
                    float val = acc[m][n][j];
                    float o = val;
                    if (sec < 2) {
                        float partner = __shfl_xor(val, 1);
                        int i0 = d >> 1;
                        float c = cosT[tt * 32 + i0], s = sinT[tt * 32 + i0];
                        o = ((d & 1) == 0) ? (val * c - partner * s)
                                           : (partner * s + val * c);
                        if (sec == 0) o *= QSCALE;
                    }
                    size_t off = (((size_t)((b * 16 + h) * 2048 + tt)) << 6) + d;
                    u16* dst = (sec == 0) ? qOut : ((sec == 1) ? kOut : vOut);
                    dst[off] = f2bf(o);
                }
            }
        }
    } else {
#pragma unroll
        for (int m = 0; m < 4; m++) {
#pragma unroll
            for (int j = 0; j < 4; j++) {
                int t = m0 + (wr << 6) + (m << 4) + (g << 2) + j;
#pragma unroll
                for (int n = 0; n < 4; n++) {
                    int col = n0 + (wc << 6) + (n << 4) + l15;
                    outF[(size_t)t * N + col] = acc[m][n][j] + bias[col];
                }
            }
        }
    }
}

// ---------------------------------------------------------------------------
// Flash attention, swapped-operand 32x32 MFMA.
// Block = 4 waves (256 thr); wave w owns 32 q-rows of a 128-row q-block.
// S^T = mfma(K, Q): lane = q-row, kv in regs -> lane-local softmax.
// P^T assembled in-register via cvt_pk_bf16 + permlane32_swap.
// O^T = mfma(V^T, P^T): lane = q-row again. K/V staged in LDS (shared by
// 4 waves), double-buffered, counted vmcnt. Waves skip steps beyond their
// diagonal; barriers stay uniform.
// ---------------------------------------------------------------------------
__device__ __forceinline__ void kv_stage2(const u16* Kb, const u16* Vtb,
                                          u16* Kl, u16* Vl, int tid, int k0) {
#pragma unroll
    for (int pp = 0; pp < 2; pp++) {
        int L = tid + (pp << 8);        // 0..511 chunks of 16B
        int row = L >> 3, c = L & 7;
        int cg = (c ^ (row & 7)) << 3;  // swizzled source column (elems)
        gload16(Kb + (((size_t)(k0 + row)) << 6) + cg, Kl + L * 8);
        gload16(Vtb + ((size_t)row << 11) + k0 + cg, Vl + L * 8);
    }
}

template <bool MASKED>
__device__ __forceinline__ void attn_step32(
    const bf16x8 (&qf)[4], f32x16 (&O)[2], float& MR, float& LR,
    const char* Kl, const char* Vl, const int (&foff)[2][4], int lim) {
    // S^T = K * Q  (subtile s: kv rows s*32..s*32+31, all 32 q cols)
    f32x16 st[2];
    __builtin_amdgcn_s_setprio(1);
#pragma unroll
    for (int s = 0; s < 2; s++) {
#pragma unroll
        for (int e = 0; e < 16; e++) st[s][e] = 0.f;
#pragma unroll
        for (int ks = 0; ks < 4; ks++) {
            bf16x8 kf = *(const bf16x8*)(Kl + foff[s][ks]);
            st[s] = __builtin_amdgcn_mfma_f32_32x32x16_bf16(kf, qf[ks], st[s], 0, 0, 0);
        }
    }
    __builtin_amdgcn_s_setprio(0);
    if (MASKED) {
#pragma unroll
        for (int s = 0; s < 2; s++) {
            const int ls = lim - (s << 5);
#pragma unroll
            for (int r = 0; r < 16; r++) {
                const int kvloc = (r & 3) + 8 * (r >> 2);
                if (kvloc > ls) st[s][r] = -1e30f;
            }
        }
    }
    // row max: in-lane tree + one cross-half swap
    float t8[8];
#pragma unroll
    for (int r = 0; r < 8; r++)
        t8[r] = fmaxf(fmaxf(st[0][r], st[0][r + 8]),
                      fmaxf(st[1][r], st[1][r + 8]));
    float m = fmaxf(fmaxf(fmaxf(t8[0], t8[4]), fmaxf(t8[1], t8[5])),
                    fmaxf(fmaxf(t8[2], t8[6]), fmaxf(t8[3], t8[7])));
    m = fmaxf(m, __shfl_xor(m, 32));
    float mn = fmaxf(MR, m);
    if (__ballot(m - MR > 10.f)) {  // defer-max
        float al = fexp2(MR - mn);
        MR = mn;
        LR *= al;
#pragma unroll
        for (int e = 0; e < 16; e++) { O[0][e] *= al; O[1][e] *= al; }
    }
    // P = exp2(S - MR) in place; 4-way interleaved sum tree
    float s0 = 0.f, s1 = 0.f, s2 = 0.f, s3 = 0.f;
#pragma unroll
    for (int s = 0; s < 2; s++)
#pragma unroll
        for (int r = 0; r < 16; r++) {
            float pv = fexp2(st[s][r] - MR);
            st[s][r] = pv;
            if ((r & 3) == 0) s0 += pv;
            else if ((r & 3) == 1) s1 += pv;
            else if ((r & 3) == 2) s2 += pv;
            else s3 += pv;
        }
    float sum = (s0 + s1) + (s2 + s3);
    sum += __shfl_xor(sum, 32);
    LR += sum;
    // P^T B-frags via cvt_pk + permlane32_swap; O^T += V^T * P^T
#pragma unroll
    for (int ks = 0; ks < 4; ks++) {
        const int sT = ks >> 1, b1 = (ks & 1) << 3;
        u32 a = cvtpk(st[sT][b1 + 0], st[sT][b1 + 1]);
        u32 b = cvtpk(st[sT][b1 + 2], st[sT][b1 + 3]);
        u32 c = cvtpk(st[sT][b1 + 4], st[sT][b1 + 5]);
        u32 d = cvtpk(st[sT][b1 + 6], st[sT][b1 + 7]);
        permswap(a, c);
        permswap(b, d);
        bf16x8 pf = __builtin_bit_cast(bf16x8, make_uint4(a, b, c, d));
        __builtin_amdgcn_s_setprio(1);
#pragma unroll
        for (int t2 = 0; t2 < 2; t2++) {
            bf16x8 vf = *(const bf16x8*)(Vl + foff[t2][ks]);
            O[t2] = __builtin_amdgcn_mfma_f32_32x32x16_bf16(vf, pf, O[t2], 0, 0, 0);
        }
        __builtin_amdgcn_s_setprio(0);
    }
}

__device__ __forceinline__ void attn_store32(
    const f32x16 (&O)[2], float LR, u16* __restrict__ Yg,
    int b, int hd, int q, int hl) {
    float inv = 1.0f / LR;
    size_t rowoff = (((size_t)(b * 2048 + q)) << 10) + (hd << 6);
#pragma unroll
    for (int t2 = 0; t2 < 2; t2++)
#pragma unroll
        for (int rg = 0; rg < 4; rg++) {
            int d0 = (rg << 3) + (hl << 2) + (t2 << 5);
            u32 lo = cvtpk(O[t2][4 * rg + 0] * inv, O[t2][4 * rg + 1] * inv);
            u32 hi = cvtpk(O[t2][4 * rg + 2] * inv, O[t2][4 * rg + 3] * inv);
            *(uint2*)&Yg[rowoff + d0] = make_uint2(lo, hi);
        }
}

__global__ __launch_bounds__(256)
void attn_mfma(const u16* __restrict__ Qg, const u16* __restrict__ Kg,
               const u16* __restrict__ Vtg, u16* __restrict__ Yg) {
    __shared__ u16 Ks[2][64 * 64];
    __shared__ u16 Vts[2][64 * 64];

    const int tid = threadIdx.x;
    const int lane = tid & 63;
    const int w = tid >> 6;           // 0..3
    const int l31 = lane & 31, hl = lane >> 5;
    const int bh = (int)blockIdx.x;   // 0..31 — bh-major for XCD/L2 locality
    const int Qi = (int)gridDim.y - 1 - (int)blockIdx.y;  // big q-blocks first
    const int b = bh >> 4, hd = bh & 15;
    const int qbw = (Qi << 7) + (w << 5);  // wave's first q-row
    const int q_lane = qbw + l31;
    const int nst = 2 * Qi + 2;            // kv tiles of 64

    const u16* Qb = Qg + ((size_t)bh << 17);
    const u16* Kb = Kg + ((size_t)bh << 17);
    const u16* Vtb = Vtg + ((size_t)bh << 17);

    // fragment byte offsets into K/V LDS (s = kv-subtile for K, d-tile for V)
    int foff[2][4];
#pragma unroll
    for (int s = 0; s < 2; s++)
#pragma unroll
        for (int ks = 0; ks < 4; ks++) {
            int row = (s << 5) + l31;
            foff[s][ks] = row * 128 + (((hl + (ks << 1)) ^ (row & 7)) << 4);
        }

    // Q B-frags direct global->register
    bf16x8 qf[4];
#pragma unroll
    for (int ks = 0; ks < 4; ks++)
        qf[ks] = *(const bf16x8*)(Qb + (((size_t)q_lane) << 6) + (hl << 3) + (ks << 4));

    f32x16 O[2];
#pragma unroll
    for (int e = 0; e < 16; e++) { O[0][e] = 0.f; O[1][e] = 0.f; }
    float MR = -1e30f, LR = 0.f;

    kv_stage2(Kb, Vtb, &Ks[0][0], &Vts[0][0], tid, 0);
    int cur = 0;

    for (int kt = 0; kt < nst; kt++) {
        if (kt + 1 < nst) {
            kv_stage2(Kb, Vtb, &Ks[cur ^ 1][0], &Vts[cur ^ 1][0], tid, (kt + 1) << 6);
            asm volatile("s_waitcnt vmcnt(4)" ::: "memory");
        } else {
            asm volatile("s_waitcnt vmcnt(0)" ::: "memory");
        }
        __builtin_amdgcn_s_barrier();
        asm volatile("" ::: "memory");
        const int kv0 = kt << 6;
        if (kv0 <= qbw + 31) {  // wave participates (uniform per wave)
            if (qbw - kv0 >= 63) {
                attn_step32<false>(qf, O, MR, LR, (const char*)&Ks[cur][0],
                                   (const char*)&Vts[cur][0], foff, 0);
            } else {
                int lim = q_lane - kv0 - (hl << 2);
                attn_step32<true>(qf, O, MR, LR, (const char*)&Ks[cur][0],
                                  (const char*)&Vts[cur][0], foff, lim);
            }
        }
        asm volatile("" ::: "memory");
        __builtin_amdgcn_s_barrier();
        cur ^= 1;
    }
    attn_store32(O, LR, Yg, b, hd, q_lane, hl);
}

// ---------------------------------------------------------------------------
extern "C" void kernel_launch(void* const* d_in, const int* in_sizes, int n_in,
                              void* d_out, int out_size, void* d_ws, size_t ws_size,
                              hipStream_t stream) {
    const float* x      = (const float*)d_in[0];
    const float* w_qkv  = (const float*)d_in[1];
    const float* w_proj = (const float*)d_in[2];
    const float* b_proj = (const float*)d_in[3];
    float* out = (float*)d_out;

    const size_t SZ = (size_t)M_ROWS * CDIM;
    char* ws = (char*)d_ws;
    u16* xb     = (u16*)ws;                ws += SZ * 2;
    u16* wqkvT  = (u16*)ws;                ws += (size_t)3 * CDIM * CDIM * 2;
    u16* wprojT = (u16*)ws;                ws += (size_t)CDIM * CDIM * 2;
    u16* Qb     = (u16*)ws;                ws += SZ * 2;
    u16* Kb     = (u16*)ws;                ws += SZ * 2;
    u16* Vb     = (u16*)ws;                ws += SZ * 2;
    u16* Vt     = (u16*)ws;                ws += SZ * 2;
    u16* Yb     = (u16*)ws;                ws += SZ * 2;
    float* cosT = (float*)ws;              ws += (size_t)T_SEQ * 32 * 4;
    float* sinT = (float*)ws;              ws += (size_t)T_SEQ * 32 * 4;

    rope_table_kernel<<<dim3(256), dim3(256), 0, stream>>>(cosT, sinT);
    conv_bf16<<<dim3(2048), dim3(256), 0, stream>>>(x, xb, (int)(SZ / 8));
    convT64<<<dim3(48, 16), dim3(256), 0, stream>>>(w_qkv, wqkvT, CDIM, 3 * CDIM);
    convT64<<<dim3(16, 16), dim3(256), 0, stream>>>(w_proj, wprojT, CDIM, CDIM);

    gemm_bf16<0><<<dim3(24, 32), dim3(256), 0, stream>>>(
        xb, wqkvT, 3 * CDIM, CDIM, nullptr, nullptr, Qb, Kb, Vb, cosT, sinT);

    transposeV<<<dim3(32, 32), dim3(256), 0, stream>>>(Vb, Vt);

    attn_mfma<<<dim3(32, 16), dim3(256), 0, stream>>>(Qb, Kb, Vt, Yb);

    gemm_bf16<1><<<dim3(8, 32), dim3(256), 0, stream>>>(
        Yb, wprojT, CDIM, CDIM, b_proj, out, nullptr, nullptr, nullptr, nullptr, nullptr);
}

// Round 6
// 209.690 us; speedup vs baseline: 1.0978x; 1.0167x over previous
//
#include <hip/hip_runtime.h>
#include <math.h>

#define T_SEQ 2048
#define CDIM  1024
#define HEADS 16
#define DHEAD 64
#define BATCH 2
#define M_ROWS 4096
#define QSCALE 0.18033688011112042f  // 0.125 * log2(e)

typedef unsigned short u16;
typedef unsigned int u32;
typedef __attribute__((ext_vector_type(8))) short bf16x8;
typedef __attribute__((ext_vector_type(4))) float f32x4;
typedef __attribute__((ext_vector_type(16))) float f32x16;

__device__ inline u16 f2bf(float f) {
    u32 u = __builtin_bit_cast(u32, f);
    u32 r = (u + 0x7fffu + ((u >> 16) & 1u)) >> 16;  // RNE
    return (u16)r;
}

__device__ inline float bf2f(u16 h) {
    u32 u = ((u32)h) << 16;
    return __builtin_bit_cast(float, u);
}

__device__ inline u32 cvtpk(float lo, float hi) {
    u32 r;
    asm("v_cvt_pk_bf16_f32 %0, %1, %2" : "=v"(r) : "v"(lo), "v"(hi));
    return r;
}

// swap: x.hi-lanes <-> y.lo-lanes  (v_permlane32_swap_b32, gfx950)
__device__ inline void permswap(u32& x, u32& y) {
    asm volatile("v_permlane32_swap_b32 %0, %1" : "+v"(x), "+v"(y));
}

__device__ inline float fexp2(float x) {
#if __has_builtin(__builtin_amdgcn_exp2f)
    return __builtin_amdgcn_exp2f(x);
#else
    float r; asm("v_exp_f32 %0, %1" : "=v"(r) : "v"(x)); return r;
#endif
}

__device__ inline void gload16(const void* g, void* l) {
    __builtin_amdgcn_global_load_lds(
        (const __attribute__((address_space(1))) void*)g,
        (__attribute__((address_space(3))) void*)l, 16, 0, 0);
}

// ---------------------------------------------------------------------------
// RoPE cos/sin table [T][32]
// ---------------------------------------------------------------------------
__global__ void rope_table_kernel(float* __restrict__ cosT, float* __restrict__ sinT) {
    int idx = blockIdx.x * blockDim.x + threadIdx.x;
    if (idx >= T_SEQ * 32) return;
    int t = idx >> 5;
    int i = idx & 31;
    float expo = (2.0f * (float)i) / 64.0f;
    float inv = powf(10000.0f, -expo);
    float a = (float)t * inv;
    cosT[idx] = cosf(a);
    sinT[idx] = sinf(a);
}

// ---------------------------------------------------------------------------
// fp32 -> bf16 elementwise (8 elems/thread)
// ---------------------------------------------------------------------------
__global__ __launch_bounds__(256)
void conv_bf16(const float* __restrict__ in, u16* __restrict__ out, int n8) {
    int i = blockIdx.x * blockDim.x + threadIdx.x;
    if (i >= n8) return;
    const float4* p = (const float4*)(in + (size_t)i * 8);
    float4 a = p[0], b = p[1];
    uint4 o;
    o.x = (u32)f2bf(a.x) | ((u32)f2bf(a.y) << 16);
    o.y = (u32)f2bf(a.z) | ((u32)f2bf(a.w) << 16);
    o.z = (u32)f2bf(b.x) | ((u32)f2bf(b.y) << 16);
    o.w = (u32)f2bf(b.z) | ((u32)f2bf(b.w) << 16);
    *(uint4*)(out + (size_t)i * 8) = o;
}

// ---------------------------------------------------------------------------
// fp32 [K][N] -> bf16 [N][K] (weight transpose+convert), 64x64 tiles
// ---------------------------------------------------------------------------
__global__ __launch_bounds__(256)
void convT64(const float* __restrict__ in, u16* __restrict__ out, int K, int N) {
    __shared__ float Ls[64][65];
    const int tid = threadIdx.x;
    const int k0 = blockIdx.y << 6, n0 = blockIdx.x << 6;
    const int r0 = tid >> 4, c4 = (tid & 15) << 2;
#pragma unroll
    for (int p = 0; p < 4; p++) {
        int r = r0 + (p << 4);
        float4 v = *(const float4*)&in[(size_t)(k0 + r) * N + n0 + c4];
        Ls[r][c4 + 0] = v.x; Ls[r][c4 + 1] = v.y;
        Ls[r][c4 + 2] = v.z; Ls[r][c4 + 3] = v.w;
    }
    __syncthreads();
    const int n = tid >> 2, kq = (tid & 3) << 4;
    u32 pk[8];
#pragma unroll
    for (int j = 0; j < 8; j++) {
        float lo = Ls[kq + 2 * j][n], hi = Ls[kq + 2 * j + 1][n];
        pk[j] = (u32)f2bf(lo) | ((u32)f2bf(hi) << 16);
    }
    u32* dst = (u32*)&out[(size_t)(n0 + n) * K + k0 + kq];
    ((uint4*)dst)[0] = make_uint4(pk[0], pk[1], pk[2], pk[3]);
    ((uint4*)dst)[1] = make_uint4(pk[4], pk[5], pk[6], pk[7]);
}

// ---------------------------------------------------------------------------
// RoPE + scatter: qkv [4096][3072] cols 0..2047 -> Qb/Kb bf16 [B,H,T,D].
// Thread owns 8 consecutive d: both members of 4 pairs local -> no shfl.
// ---------------------------------------------------------------------------
__global__ __launch_bounds__(256)
void ropeQK(const u16* __restrict__ qkv, u16* __restrict__ Qb, u16* __restrict__ Kb,
            const float* __restrict__ cosT, const float* __restrict__ sinT) {
    int L = blockIdx.x * 256 + threadIdx.x;  // 1M threads
    int m = L >> 8;          // row 0..4095
    int col0 = (L & 255) << 3;
    int sec = col0 >> 10;    // 0=q, 1=k
    int cc = col0 & 1023;
    int h = cc >> 6, d0 = cc & 63;
    int b = m >> 11, t = m & 2047;

    uint4 v = *(const uint4*)&qkv[(size_t)m * 3072 + col0];
    float e0 = bf2f((u16)v.x), o0 = bf2f((u16)(v.x >> 16));
    float e1 = bf2f((u16)v.y), o1 = bf2f((u16)(v.y >> 16));
    float e2 = bf2f((u16)v.z), o2 = bf2f((u16)(v.z >> 16));
    float e3 = bf2f((u16)v.w), o3 = bf2f((u16)(v.w >> 16));

    int i0 = d0 >> 1;  // multiple of 4
    float4 c4v = *(const float4*)&cosT[t * 32 + i0];
    float4 s4v = *(const float4*)&sinT[t * 32 + i0];

    float re0 = e0 * c4v.x - o0 * s4v.x, ro0 = e0 * s4v.x + o0 * c4v.x;
    float re1 = e1 * c4v.y - o1 * s4v.y, ro1 = e1 * s4v.y + o1 * c4v.y;
    float re2 = e2 * c4v.z - o2 * s4v.z, ro2 = e2 * s4v.z + o2 * c4v.z;
    float re3 = e3 * c4v.w - o3 * s4v.w, ro3 = e3 * s4v.w + o3 * c4v.w;

    if (sec == 0) {
        re0 *= QSCALE; ro0 *= QSCALE; re1 *= QSCALE; ro1 *= QSCALE;
        re2 *= QSCALE; ro2 *= QSCALE; re3 *= QSCALE; ro3 *= QSCALE;
    }
    uint4 o;
    o.x = cvtpk(re0, ro0); o.y = cvtpk(re1, ro1);
    o.z = cvtpk(re2, ro2); o.w = cvtpk(re3, ro3);
    u16* dst = (sec == 0) ? Qb : Kb;
    *(uint4*)&dst[(((size_t)((b * 16 + h) * 2048 + t)) << 6) + d0] = o;
}

// ---------------------------------------------------------------------------
// V-section of qkv [4096][3072] (cols 2048..3071) -> Vt [bh][64][2048]
// ---------------------------------------------------------------------------
__global__ __launch_bounds__(256)
void transposeV2(const u16* __restrict__ qkv, u16* __restrict__ out) {
    __shared__ u16 Ls[64][72];
    const int tid = threadIdx.x;
    const int bh = blockIdx.y;
    const int b = bh >> 4, h = bh & 15;
    const int t0 = blockIdx.x << 6;
    const u16* src = qkv + (size_t)(b * 2048 + t0) * 3072 + 2048 + (h << 6);
#pragma unroll
    for (int p = 0; p < 2; p++) {
        int L = tid + (p << 8);
        int t = L >> 3, c = L & 7;
        uint4 v = *(const uint4*)&src[(size_t)t * 3072 + (c << 3)];
        *(uint4*)&Ls[t][c << 3] = v;
    }
    __syncthreads();
    const int d = tid >> 2, tq = (tid & 3) << 4;
    u32 pk[8];
#pragma unroll
    for (int j = 0; j < 8; j++) {
        u16 lo = Ls[tq + 2 * j][d], hi = Ls[tq + 2 * j + 1][d];
        pk[j] = (u32)lo | ((u32)hi << 16);
    }
    u16* dst = out + ((size_t)bh << 17) + ((size_t)d << 11) + t0 + tq;
    ((uint4*)dst)[0] = make_uint4(pk[0], pk[1], pk[2], pk[3]);
    ((uint4*)dst)[1] = make_uint4(pk[4], pk[5], pk[6], pk[7]);
}

// ---------------------------------------------------------------------------
// bf16 MFMA GEMM, 128x128 tile, BK=32, dbl-buffered LDS + counted vmcnt.
// EPI=0: plain bf16 [M][N] store.  EPI=1: +bias, fp32 [M][N] store.
// ---------------------------------------------------------------------------
template <int EPI>
__global__ __launch_bounds__(256)
void gemm_bf16(const u16* __restrict__ A, const u16* __restrict__ Bt,
               int N, int K,
               const float* __restrict__ bias, float* __restrict__ outF,
               u16* __restrict__ outB) {
    __shared__ u16 Alds[2][128 * 32];
    __shared__ u16 Blds[2][128 * 32];
    const int tid = threadIdx.x;
    const int lane = tid & 63;
    const int w = tid >> 6;
    const int wr = w >> 1, wc = w & 1;
    const int g = lane >> 4, l15 = lane & 15;
    const int m0 = blockIdx.y * 128, n0 = blockIdx.x * 128;

    f32x4 acc[4][4];
#pragma unroll
    for (int m = 0; m < 4; m++)
#pragma unroll
        for (int n = 0; n < 4; n++)
#pragma unroll
            for (int e = 0; e < 4; e++) acc[m][n][e] = 0.f;

    int aoff[4], boff[4];
#pragma unroll
    for (int m = 0; m < 4; m++) {
        aoff[m] = ((wr << 6) + (m << 4) + l15) * 64 + (g << 4);
        boff[m] = ((wc << 6) + (m << 4) + l15) * 64 + (g << 4);
    }
    const int rowA0 = tid >> 2, kk0 = (tid & 3) << 3;

#define GSTAGE(BUF, K0)                                                          \
    {                                                                            \
        _Pragma("unroll") for (int pq = 0; pq < 2; pq++) {                       \
            int L = tid + (pq << 8);                                             \
            int row = rowA0 + (pq << 6);                                         \
            gload16(A + (size_t)(m0 + row) * K + (K0) + kk0, &Alds[BUF][0] + L * 8); \
            gload16(Bt + (size_t)(n0 + row) * K + (K0) + kk0, &Blds[BUF][0] + L * 8); \
        }                                                                        \
    }

    GSTAGE(0, 0);
    const int nt = K >> 5;
    int cur = 0;
    for (int t = 0; t < nt; t++) {
        if (t + 1 < nt) {
            GSTAGE(cur ^ 1, ((t + 1) << 5));
            asm volatile("s_waitcnt vmcnt(4)" ::: "memory");
        } else {
            asm volatile("s_waitcnt vmcnt(0)" ::: "memory");
        }
        __builtin_amdgcn_s_barrier();
        asm volatile("" ::: "memory");
        bf16x8 af[4], bfr[4];
#pragma unroll
        for (int m = 0; m < 4; m++) af[m] = *(const bf16x8*)((const char*)&Alds[cur][0] + aoff[m]);
#pragma unroll
        for (int n = 0; n < 4; n++) bfr[n] = *(const bf16x8*)((const char*)&Blds[cur][0] + boff[n]);
#pragma unroll
        for (int m = 0; m < 4; m++)
#pragma unroll
            for (int n = 0; n < 4; n++)
                acc[m][n] = __builtin_amdgcn_mfma_f32_16x16x32_bf16(af[m], bfr[n], acc[m][n], 0, 0, 0);
        asm volatile("" ::: "memory");
        __builtin_amdgcn_s_barrier();
        cur ^= 1;
    }
#undef GSTAGE

    if (EPI == 0) {
#pragma unroll
        for (int m = 0; m < 4; m++) {
#pragma unroll
            for (int j = 0; j < 4; j++) {
                int t = m0 + (wr << 6) + (m << 4) + (g << 2) + j;
                u16* rowp = outB + (size_t)t * N;
#pragma unroll
                for (int n = 0; n < 4; n++) {
                    int col = n0 + (wc << 6) + (n << 4) + l15;
                    rowp[col] = f2bf(acc[m][n][j]);
                }
            }
        }
    } else {
#pragma unroll
        for (int m = 0; m < 4; m++) {
#pragma unroll
            for (int j = 0; j < 4; j++) {
                int t = m0 + (wr << 6) + (m << 4) + (g << 2) + j;
#pragma unroll
                for (int n = 0; n < 4; n++) {
                    int col = n0 + (wc << 6) + (n << 4) + l15;
                    outF[(size_t)t * N + col] = acc[m][n][j] + bias[col];
                }
            }
        }
    }
}

// ---------------------------------------------------------------------------
// Flash attention, swapped-operand 32x32 MFMA (unchanged from round 5).
// ---------------------------------------------------------------------------
__device__ __forceinline__ void kv_stage2(const u16* Kb, const u16* Vtb,
                                          u16* Kl, u16* Vl, int tid, int k0) {
#pragma unroll
    for (int pp = 0; pp < 2; pp++) {
        int L = tid + (pp << 8);
        int row = L >> 3, c = L & 7;
        int cg = (c ^ (row & 7)) << 3;
        gload16(Kb + (((size_t)(k0 + row)) << 6) + cg, Kl + L * 8);
        gload16(Vtb + ((size_t)row << 11) + k0 + cg, Vl + L * 8);
    }
}

template <bool MASKED>
__device__ __forceinline__ void attn_step32(
    const bf16x8 (&qf)[4], f32x16 (&O)[2], float& MR, float& LR,
    const char* Kl, const char* Vl, const int (&foff)[2][4], int lim) {
    f32x16 st[2];
    __builtin_amdgcn_s_setprio(1);
#pragma unroll
    for (int s = 0; s < 2; s++) {
#pragma unroll
        for (int e = 0; e < 16; e++) st[s][e] = 0.f;
#pragma unroll
        for (int ks = 0; ks < 4; ks++) {
            bf16x8 kf = *(const bf16x8*)(Kl + foff[s][ks]);
            st[s] = __builtin_amdgcn_mfma_f32_32x32x16_bf16(kf, qf[ks], st[s], 0, 0, 0);
        }
    }
    __builtin_amdgcn_s_setprio(0);
    if (MASKED) {
#pragma unroll
        for (int s = 0; s < 2; s++) {
            const int ls = lim - (s << 5);
#pragma unroll
            for (int r = 0; r < 16; r++) {
                const int kvloc = (r & 3) + 8 * (r >> 2);
                if (kvloc > ls) st[s][r] = -1e30f;
            }
        }
    }
    float t8[8];
#pragma unroll
    for (int r = 0; r < 8; r++)
        t8[r] = fmaxf(fmaxf(st[0][r], st[0][r + 8]),
                      fmaxf(st[1][r], st[1][r + 8]));
    float m = fmaxf(fmaxf(fmaxf(t8[0], t8[4]), fmaxf(t8[1], t8[5])),
                    fmaxf(fmaxf(t8[2], t8[6]), fmaxf(t8[3], t8[7])));
    m = fmaxf(m, __shfl_xor(m, 32));
    float mn = fmaxf(MR, m);
    if (__ballot(m - MR > 10.f)) {
        float al = fexp2(MR - mn);
        MR = mn;
        LR *= al;
#pragma unroll
        for (int e = 0; e < 16; e++) { O[0][e] *= al; O[1][e] *= al; }
    }
    float s0 = 0.f, s1 = 0.f, s2 = 0.f, s3 = 0.f;
#pragma unroll
    for (int s = 0; s < 2; s++)
#pragma unroll
        for (int r = 0; r < 16; r++) {
            float pv = fexp2(st[s][r] - MR);
            st[s][r] = pv;
            if ((r & 3) == 0) s0 += pv;
            else if ((r & 3) == 1) s1 += pv;
            else if ((r & 3) == 2) s2 += pv;
            else s3 += pv;
        }
    float sum = (s0 + s1) + (s2 + s3);
    sum += __shfl_xor(sum, 32);
    LR += sum;
#pragma unroll
    for (int ks = 0; ks < 4; ks++) {
        const int sT = ks >> 1, b1 = (ks & 1) << 3;
        u32 a = cvtpk(st[sT][b1 + 0], st[sT][b1 + 1]);
        u32 b = cvtpk(st[sT][b1 + 2], st[sT][b1 + 3]);
        u32 c = cvtpk(st[sT][b1 + 4], st[sT][b1 + 5]);
        u32 d = cvtpk(st[sT][b1 + 6], st[sT][b1 + 7]);
        permswap(a, c);
        permswap(b, d);
        bf16x8 pf = __builtin_bit_cast(bf16x8, make_uint4(a, b, c, d));
        __builtin_amdgcn_s_setprio(1);
#pragma unroll
        for (int t2 = 0; t2 < 2; t2++) {
            bf16x8 vf = *(const bf16x8*)(Vl + foff[t2][ks]);
            O[t2] = __builtin_amdgcn_mfma_f32_32x32x16_bf16(vf, pf, O[t2], 0, 0, 0);
        }
        __builtin_amdgcn_s_setprio(0);
    }
}

__device__ __forceinline__ void attn_store32(
    const f32x16 (&O)[2], float LR, u16* __restrict__ Yg,
    int b, int hd, int q, int hl) {
    float inv = 1.0f / LR;
    size_t rowoff = (((size_t)(b * 2048 + q)) << 10) + (hd << 6);
#pragma unroll
    for (int t2 = 0; t2 < 2; t2++)
#pragma unroll
        for (int rg = 0; rg < 4; rg++) {
            int d0 = (rg << 3) + (hl << 2) + (t2 << 5);
            u32 lo = cvtpk(O[t2][4 * rg + 0] * inv, O[t2][4 * rg + 1] * inv);
            u32 hi = cvtpk(O[t2][4 * rg + 2] * inv, O[t2][4 * rg + 3] * inv);
            *(uint2*)&Yg[rowoff + d0] = make_uint2(lo, hi);
        }
}

__global__ __launch_bounds__(256)
void attn_mfma(const u16* __restrict__ Qg, const u16* __restrict__ Kg,
               const u16* __restrict__ Vtg, u16* __restrict__ Yg) {
    __shared__ u16 Ks[2][64 * 64];
    __shared__ u16 Vts[2][64 * 64];

    const int tid = threadIdx.x;
    const int lane = tid & 63;
    const int w = tid >> 6;
    const int l31 = lane & 31, hl = lane >> 5;
    const int bh = (int)blockIdx.x;
    const int Qi = (int)gridDim.y - 1 - (int)blockIdx.y;
    const int b = bh >> 4, hd = bh & 15;
    const int qbw = (Qi << 7) + (w << 5);
    const int q_lane = qbw + l31;
    const int nst = 2 * Qi + 2;

    const u16* Qb = Qg + ((size_t)bh << 17);
    const u16* Kb = Kg + ((size_t)bh << 17);
    const u16* Vtb = Vtg + ((size_t)bh << 17);

    int foff[2][4];
#pragma unroll
    for (int s = 0; s < 2; s++)
#pragma unroll
        for (int ks = 0; ks < 4; ks++) {
            int row = (s << 5) + l31;
            foff[s][ks] = row * 128 + (((hl + (ks << 1)) ^ (row & 7)) << 4);
        }

    bf16x8 qf[4];
#pragma unroll
    for (int ks = 0; ks < 4; ks++)
        qf[ks] = *(const bf16x8*)(Qb + (((size_t)q_lane) << 6) + (hl << 3) + (ks << 4));

    f32x16 O[2];
#pragma unroll
    for (int e = 0; e < 16; e++) { O[0][e] = 0.f; O[1][e] = 0.f; }
    float MR = -1e30f, LR = 0.f;

    kv_stage2(Kb, Vtb, &Ks[0][0], &Vts[0][0], tid, 0);
    int cur = 0;

    for (int kt = 0; kt < nst; kt++) {
        if (kt + 1 < nst) {
            kv_stage2(Kb, Vtb, &Ks[cur ^ 1][0], &Vts[cur ^ 1][0], tid, (kt + 1) << 6);
            asm volatile("s_waitcnt vmcnt(4)" ::: "memory");
        } else {
            asm volatile("s_waitcnt vmcnt(0)" ::: "memory");
        }
        __builtin_amdgcn_s_barrier();
        asm volatile("" ::: "memory");
        const int kv0 = kt << 6;
        if (kv0 <= qbw + 31) {
            if (qbw - kv0 >= 63) {
                attn_step32<false>(qf, O, MR, LR, (const char*)&Ks[cur][0],
                                   (const char*)&Vts[cur][0], foff, 0);
            } else {
                int lim = q_lane - kv0 - (hl << 2);
                attn_step32<true>(qf, O, MR, LR, (const char*)&Ks[cur][0],
                                  (const char*)&Vts[cur][0], foff, lim);
            }
        }
        asm volatile("" ::: "memory");
        __builtin_amdgcn_s_barrier();
        cur ^= 1;
    }
    attn_store32(O, LR, Yg, b, hd, q_lane, hl);
}

// ---------------------------------------------------------------------------
extern "C" void kernel_launch(void* const* d_in, const int* in_sizes, int n_in,
                              void* d_out, int out_size, void* d_ws, size_t ws_size,
                              hipStream_t stream) {
    const float* x      = (const float*)d_in[0];
    const float* w_qkv  = (const float*)d_in[1];
    const float* w_proj = (const float*)d_in[2];
    const float* b_proj = (const float*)d_in[3];
    float* out = (float*)d_out;

    const size_t SZ = (size_t)M_ROWS * CDIM;
    char* ws = (char*)d_ws;
    u16* xb     = (u16*)ws;                ws += SZ * 2;
    u16* wqkvT  = (u16*)ws;                ws += (size_t)3 * CDIM * CDIM * 2;
    u16* wprojT = (u16*)ws;                ws += (size_t)CDIM * CDIM * 2;
    u16* qkvb   = (u16*)ws;                ws += (size_t)M_ROWS * 3 * CDIM * 2;
    u16* Qb     = (u16*)ws;                ws += SZ * 2;
    u16* Kb     = (u16*)ws;                ws += SZ * 2;
    u16* Vt     = (u16*)ws;                ws += SZ * 2;
    float* cosT = (float*)ws;              ws += (size_t)T_SEQ * 32 * 4;
    float* sinT = (float*)ws;              ws += (size_t)T_SEQ * 32 * 4;
    u16* Yb = qkvb;  // alias: qkvb fully consumed before attn writes Yb

    rope_table_kernel<<<dim3(256), dim3(256), 0, stream>>>(cosT, sinT);
    conv_bf16<<<dim3(2048), dim3(256), 0, stream>>>(x, xb, (int)(SZ / 8));
    convT64<<<dim3(48, 16), dim3(256), 0, stream>>>(w_qkv, wqkvT, CDIM, 3 * CDIM);
    convT64<<<dim3(16, 16), dim3(256), 0, stream>>>(w_proj, wprojT, CDIM, CDIM);

    // qkv = xb @ wqkvT  -> bf16 [4096][3072] coalesced
    gemm_bf16<0><<<dim3(24, 32), dim3(256), 0, stream>>>(
        xb, wqkvT, 3 * CDIM, CDIM, nullptr, nullptr, qkvb);

    // RoPE q,k (+QSCALE on q) -> [B,H,T,D]; V -> [B,H,D,T]
    ropeQK<<<dim3(4096), dim3(256), 0, stream>>>(qkvb, Qb, Kb, cosT, sinT);
    transposeV2<<<dim3(32, 32), dim3(256), 0, stream>>>(qkvb, Vt);

    attn_mfma<<<dim3(32, 16), dim3(256), 0, stream>>>(Qb, Kb, Vt, Yb);

    gemm_bf16<1><<<dim3(8, 32), dim3(256), 0, stream>>>(
        Yb, wprojT, CDIM, CDIM, b_proj, out, nullptr);
}

// Round 8
// 205.834 us; speedup vs baseline: 1.1184x; 1.0187x over previous
//
#include <hip/hip_runtime.h>
#include <math.h>

#define T_SEQ 2048
#define CDIM  1024
#define HEADS 16
#define DHEAD 64
#define BATCH 2
#define M_ROWS 4096
#define QSCALE 0.18033688011112042f  // 0.125 * log2(e)

typedef unsigned short u16;
typedef unsigned int u32;
typedef __attribute__((ext_vector_type(8))) short bf16x8;
typedef __attribute__((ext_vector_type(4))) float f32x4;
typedef __attribute__((ext_vector_type(16))) float f32x16;

__device__ inline u16 f2bf(float f) {
    u32 u = __builtin_bit_cast(u32, f);
    u32 r = (u + 0x7fffu + ((u >> 16) & 1u)) >> 16;  // RNE
    return (u16)r;
}

__device__ inline float bf2f(u16 h) {
    u32 u = ((u32)h) << 16;
    return __builtin_bit_cast(float, u);
}

__device__ inline u32 cvtpk(float lo, float hi) {
    u32 r;
    asm("v_cvt_pk_bf16_f32 %0, %1, %2" : "=v"(r) : "v"(lo), "v"(hi));
    return r;
}

// swap: x.hi-lanes <-> y.lo-lanes  (v_permlane32_swap_b32, gfx950)
__device__ inline void permswap(u32& x, u32& y) {
    asm volatile("v_permlane32_swap_b32 %0, %1" : "+v"(x), "+v"(y));
}

__device__ inline float fexp2(float x) {
#if __has_builtin(__builtin_amdgcn_exp2f)
    return __builtin_amdgcn_exp2f(x);
#else
    float r; asm("v_exp_f32 %0, %1" : "=v"(r) : "v"(x)); return r;
#endif
}

__device__ inline void gload16(const void* g, void* l) {
    __builtin_amdgcn_global_load_lds(
        (const __attribute__((address_space(1))) void*)g,
        (__attribute__((address_space(3))) void*)l, 16, 0, 0);
}

// ---------------------------------------------------------------------------
// RoPE cos/sin table [T][32]
// ---------------------------------------------------------------------------
__global__ void rope_table_kernel(float* __restrict__ cosT, float* __restrict__ sinT) {
    int idx = blockIdx.x * blockDim.x + threadIdx.x;
    if (idx >= T_SEQ * 32) return;
    int t = idx >> 5;
    int i = idx & 31;
    float expo = (2.0f * (float)i) / 64.0f;
    float inv = powf(10000.0f, -expo);
    float a = (float)t * inv;
    cosT[idx] = cosf(a);
    sinT[idx] = sinf(a);
}

// ---------------------------------------------------------------------------
// fp32 -> bf16 elementwise (8 elems/thread)
// ---------------------------------------------------------------------------
__global__ __launch_bounds__(256)
void conv_bf16(const float* __restrict__ in, u16* __restrict__ out, int n8) {
    int i = blockIdx.x * blockDim.x + threadIdx.x;
    if (i >= n8) return;
    const float4* p = (const float4*)(in + (size_t)i * 8);
    float4 a = p[0], b = p[1];
    uint4 o;
    o.x = (u32)f2bf(a.x) | ((u32)f2bf(a.y) << 16);
    o.y = (u32)f2bf(a.z) | ((u32)f2bf(a.w) << 16);
    o.z = (u32)f2bf(b.x) | ((u32)f2bf(b.y) << 16);
    o.w = (u32)f2bf(b.z) | ((u32)f2bf(b.w) << 16);
    *(uint4*)(out + (size_t)i * 8) = o;
}

// ---------------------------------------------------------------------------
// fp32 [K][N] -> bf16 [N][K] (weight transpose+convert), 64x64 tiles
// ---------------------------------------------------------------------------
__global__ __launch_bounds__(256)
void convT64(const float* __restrict__ in, u16* __restrict__ out, int K, int N) {
    __shared__ float Ls[64][65];
    const int tid = threadIdx.x;
    const int k0 = blockIdx.y << 6, n0 = blockIdx.x << 6;
    const int r0 = tid >> 4, c4 = (tid & 15) << 2;
#pragma unroll
    for (int p = 0; p < 4; p++) {
        int r = r0 + (p << 4);
        float4 v = *(const float4*)&in[(size_t)(k0 + r) * N + n0 + c4];
        Ls[r][c4 + 0] = v.x; Ls[r][c4 + 1] = v.y;
        Ls[r][c4 + 2] = v.z; Ls[r][c4 + 3] = v.w;
    }
    __syncthreads();
    const int n = tid >> 2, kq = (tid & 3) << 4;
    u32 pk[8];
#pragma unroll
    for (int j = 0; j < 8; j++) {
        float lo = Ls[kq + 2 * j][n], hi = Ls[kq + 2 * j + 1][n];
        pk[j] = (u32)f2bf(lo) | ((u32)f2bf(hi) << 16);
    }
    u32* dst = (u32*)&out[(size_t)(n0 + n) * K + k0 + kq];
    ((uint4*)dst)[0] = make_uint4(pk[0], pk[1], pk[2], pk[3]);
    ((uint4*)dst)[1] = make_uint4(pk[4], pk[5], pk[6], pk[7]);
}

// ---------------------------------------------------------------------------
// RoPE + scatter: qkv [4096][3072] cols 0..2047 -> Qb/Kb bf16 [B,H,T,D].
// ---------------------------------------------------------------------------
__global__ __launch_bounds__(256)
void ropeQK(const u16* __restrict__ qkv, u16* __restrict__ Qb, u16* __restrict__ Kb,
            const float* __restrict__ cosT, const float* __restrict__ sinT) {
    int L = blockIdx.x * 256 + threadIdx.x;  // 1M threads
    int m = L >> 8;
    int col0 = (L & 255) << 3;
    int sec = col0 >> 10;
    int cc = col0 & 1023;
    int h = cc >> 6, d0 = cc & 63;
    int b = m >> 11, t = m & 2047;

    uint4 v = *(const uint4*)&qkv[(size_t)m * 3072 + col0];
    float e0 = bf2f((u16)v.x), o0 = bf2f((u16)(v.x >> 16));
    float e1 = bf2f((u16)v.y), o1 = bf2f((u16)(v.y >> 16));
    float e2 = bf2f((u16)v.z), o2 = bf2f((u16)(v.z >> 16));
    float e3 = bf2f((u16)v.w), o3 = bf2f((u16)(v.w >> 16));

    int i0 = d0 >> 1;
    float4 c4v = *(const float4*)&cosT[t * 32 + i0];
    float4 s4v = *(const float4*)&sinT[t * 32 + i0];

    float re0 = e0 * c4v.x - o0 * s4v.x, ro0 = e0 * s4v.x + o0 * c4v.x;
    float re1 = e1 * c4v.y - o1 * s4v.y, ro1 = e1 * s4v.y + o1 * c4v.y;
    float re2 = e2 * c4v.z - o2 * s4v.z, ro2 = e2 * s4v.z + o2 * c4v.z;
    float re3 = e3 * c4v.w - o3 * s4v.w, ro3 = e3 * s4v.w + o3 * c4v.w;

    if (sec == 0) {
        re0 *= QSCALE; ro0 *= QSCALE; re1 *= QSCALE; ro1 *= QSCALE;
        re2 *= QSCALE; ro2 *= QSCALE; re3 *= QSCALE; ro3 *= QSCALE;
    }
    uint4 o;
    o.x = cvtpk(re0, ro0); o.y = cvtpk(re1, ro1);
    o.z = cvtpk(re2, ro2); o.w = cvtpk(re3, ro3);
    u16* dst = (sec == 0) ? Qb : Kb;
    *(uint4*)&dst[(((size_t)((b * 16 + h) * 2048 + t)) << 6) + d0] = o;
}

// ---------------------------------------------------------------------------
// V-section of qkv [4096][3072] (cols 2048..3071) -> Vt [bh][64][2048]
// ---------------------------------------------------------------------------
__global__ __launch_bounds__(256)
void transposeV2(const u16* __restrict__ qkv, u16* __restrict__ out) {
    __shared__ u16 Ls[64][72];
    const int tid = threadIdx.x;
    const int bh = blockIdx.y;
    const int b = bh >> 4, h = bh & 15;
    const int t0 = blockIdx.x << 6;
    const u16* src = qkv + (size_t)(b * 2048 + t0) * 3072 + 2048 + (h << 6);
#pragma unroll
    for (int p = 0; p < 2; p++) {
        int L = tid + (p << 8);
        int t = L >> 3, c = L & 7;
        uint4 v = *(const uint4*)&src[(size_t)t * 3072 + (c << 3)];
        *(uint4*)&Ls[t][c << 3] = v;
    }
    __syncthreads();
    const int d = tid >> 2, tq = (tid & 3) << 4;
    u32 pk[8];
#pragma unroll
    for (int j = 0; j < 8; j++) {
        u16 lo = Ls[tq + 2 * j][d], hi = Ls[tq + 2 * j + 1][d];
        pk[j] = (u32)lo | ((u32)hi << 16);
    }
    u16* dst = out + ((size_t)bh << 17) + ((size_t)d << 11) + t0 + tq;
    ((uint4*)dst)[0] = make_uint4(pk[0], pk[1], pk[2], pk[3]);
    ((uint4*)dst)[1] = make_uint4(pk[4], pk[5], pk[6], pk[7]);
}

// ---------------------------------------------------------------------------
// bf16 MFMA GEMM, 128x128 tile, BK=32, dbl-buffered + counted vmcnt.
// Plain bf16 [M][N] store (used for qkv).
// ---------------------------------------------------------------------------
__global__ __launch_bounds__(256)
void gemm_bf16(const u16* __restrict__ A, const u16* __restrict__ Bt,
               int N, int K, u16* __restrict__ outB) {
    __shared__ u16 Alds[2][128 * 32];
    __shared__ u16 Blds[2][128 * 32];
    const int tid = threadIdx.x;
    const int lane = tid & 63;
    const int w = tid >> 6;
    const int wr = w >> 1, wc = w & 1;
    const int g = lane >> 4, l15 = lane & 15;
    const int m0 = blockIdx.y * 128, n0 = blockIdx.x * 128;

    f32x4 acc[4][4];
#pragma unroll
    for (int m = 0; m < 4; m++)
#pragma unroll
        for (int n = 0; n < 4; n++)
#pragma unroll
            for (int e = 0; e < 4; e++) acc[m][n][e] = 0.f;

    int aoff[4], boff[4];
#pragma unroll
    for (int m = 0; m < 4; m++) {
        aoff[m] = ((wr << 6) + (m << 4) + l15) * 64 + (g << 4);
        boff[m] = ((wc << 6) + (m << 4) + l15) * 64 + (g << 4);
    }
    const int rowA0 = tid >> 2, kk0 = (tid & 3) << 3;

#define GSTAGE(BUF, K0)                                                          \
    {                                                                            \
        _Pragma("unroll") for (int pq = 0; pq < 2; pq++) {                       \
            int L = tid + (pq << 8);                                             \
            int row = rowA0 + (pq << 6);                                         \
            gload16(A + (size_t)(m0 + row) * K + (K0) + kk0, &Alds[BUF][0] + L * 8); \
            gload16(Bt + (size_t)(n0 + row) * K + (K0) + kk0, &Blds[BUF][0] + L * 8); \
        }                                                                        \
    }

    GSTAGE(0, 0);
    const int nt = K >> 5;
    int cur = 0;
    for (int t = 0; t < nt; t++) {
        if (t + 1 < nt) {
            GSTAGE(cur ^ 1, ((t + 1) << 5));
            asm volatile("s_waitcnt vmcnt(4)" ::: "memory");
        } else {
            asm volatile("s_waitcnt vmcnt(0)" ::: "memory");
        }
        __builtin_amdgcn_s_barrier();
        asm volatile("" ::: "memory");
        bf16x8 af[4], bfr[4];
#pragma unroll
        for (int m = 0; m < 4; m++) af[m] = *(const bf16x8*)((const char*)&Alds[cur][0] + aoff[m]);
#pragma unroll
        for (int n = 0; n < 4; n++) bfr[n] = *(const bf16x8*)((const char*)&Blds[cur][0] + boff[n]);
#pragma unroll
        for (int m = 0; m < 4; m++)
#pragma unroll
            for (int n = 0; n < 4; n++)
                acc[m][n] = __builtin_amdgcn_mfma_f32_16x16x32_bf16(af[m], bfr[n], acc[m][n], 0, 0, 0);
        asm volatile("" ::: "memory");
        __builtin_amdgcn_s_barrier();
        cur ^= 1;
    }
#undef GSTAGE

#pragma unroll
    for (int m = 0; m < 4; m++) {
#pragma unroll
        for (int j = 0; j < 4; j++) {
            int t = m0 + (wr << 6) + (m << 4) + (g << 2) + j;
            u16* rowp = outB + (size_t)t * N;
#pragma unroll
            for (int n = 0; n < 4; n++) {
                int col = n0 + (wc << 6) + (n << 4) + l15;
                rowp[col] = f2bf(acc[m][n][j]);
            }
        }
    }
}

// ---------------------------------------------------------------------------
// bf16 MFMA GEMM, 128x64 tile, BK=32 (proj): grid 16x32 = 512 blocks (2/CU).
// +bias, fp32 [M][N] store.
// ---------------------------------------------------------------------------
__global__ __launch_bounds__(256)
void gemm_n64(const u16* __restrict__ A, const u16* __restrict__ Bt,
              int N, int K, const float* __restrict__ bias,
              float* __restrict__ outF) {
    __shared__ u16 Alds[2][128 * 32];
    __shared__ u16 Blds[2][64 * 32];
    const int tid = threadIdx.x;
    const int lane = tid & 63;
    const int w = tid >> 6;
    const int wr = w >> 1, wc = w & 1;
    const int g = lane >> 4, l15 = lane & 15;
    const int m0 = blockIdx.y * 128, n0 = blockIdx.x * 64;

    f32x4 acc[4][2];
#pragma unroll
    for (int m = 0; m < 4; m++)
#pragma unroll
        for (int n = 0; n < 2; n++)
#pragma unroll
            for (int e = 0; e < 4; e++) acc[m][n][e] = 0.f;

    int aoff[4], boff[2];
#pragma unroll
    for (int m = 0; m < 4; m++)
        aoff[m] = ((wr << 6) + (m << 4) + l15) * 64 + (g << 4);
#pragma unroll
    for (int n = 0; n < 2; n++)
        boff[n] = ((wc << 5) + (n << 4) + l15) * 64 + (g << 4);
    const int rowA0 = tid >> 2, kk0 = (tid & 3) << 3;

#define GSTAGE64(BUF, K0)                                                        \
    {                                                                            \
        _Pragma("unroll") for (int pq = 0; pq < 2; pq++) {                       \
            int L = tid + (pq << 8);                                             \
            int row = rowA0 + (pq << 6);                                         \
            gload16(A + (size_t)(m0 + row) * K + (K0) + kk0, &Alds[BUF][0] + L * 8); \
        }                                                                        \
        gload16(Bt + (size_t)(n0 + rowA0) * K + (K0) + kk0, &Blds[BUF][0] + tid * 8); \
    }

    GSTAGE64(0, 0);
    const int nt = K >> 5;
    int cur = 0;
    for (int t = 0; t < nt; t++) {
        if (t + 1 < nt) {
            GSTAGE64(cur ^ 1, ((t + 1) << 5));
            asm volatile("s_waitcnt vmcnt(3)" ::: "memory");
        } else {
            asm volatile("s_waitcnt vmcnt(0)" ::: "memory");
        }
        __builtin_amdgcn_s_barrier();
        asm volatile("" ::: "memory");
        bf16x8 af[4], bfr[2];
#pragma unroll
        for (int m = 0; m < 4; m++) af[m] = *(const bf16x8*)((const char*)&Alds[cur][0] + aoff[m]);
#pragma unroll
        for (int n = 0; n < 2; n++) bfr[n] = *(const bf16x8*)((const char*)&Blds[cur][0] + boff[n]);
#pragma unroll
        for (int m = 0; m < 4; m++)
#pragma unroll
            for (int n = 0; n < 2; n++)
                acc[m][n] = __builtin_amdgcn_mfma_f32_16x16x32_bf16(af[m], bfr[n], acc[m][n], 0, 0, 0);
        asm volatile("" ::: "memory");
        __builtin_amdgcn_s_barrier();
        cur ^= 1;
    }
#undef GSTAGE64

#pragma unroll
    for (int m = 0; m < 4; m++) {
#pragma unroll
        for (int j = 0; j < 4; j++) {
            int t = m0 + (wr << 6) + (m << 4) + (g << 2) + j;
#pragma unroll
            for (int n = 0; n < 2; n++) {
                int col = n0 + (wc << 5) + (n << 4) + l15;
                outF[(size_t)t * N + col] = acc[m][n][j] + bias[col];
            }
        }
    }
}

// ---------------------------------------------------------------------------
// Flash attention, swapped-operand 32x32 MFMA (round-6 monolith, known-good).
// Block = 4 waves (256 thr); wave w owns 32 q-rows of a 128-row q-block.
// ---------------------------------------------------------------------------
__device__ __forceinline__ void kv_stage2(const u16* Kb, const u16* Vtb,
                                          u16* Kl, u16* Vl, int tid, int k0) {
#pragma unroll
    for (int pp = 0; pp < 2; pp++) {
        int L = tid + (pp << 8);
        int row = L >> 3, c = L & 7;
        int cg = (c ^ (row & 7)) << 3;
        gload16(Kb + (((size_t)(k0 + row)) << 6) + cg, Kl + L * 8);
        gload16(Vtb + ((size_t)row << 11) + k0 + cg, Vl + L * 8);
    }
}

template <bool MASKED>
__device__ __forceinline__ void attn_step32(
    const bf16x8 (&qf)[4], f32x16 (&O)[2], float& MR, float& LR,
    const char* Kl, const char* Vl, const int (&foff)[2][4], int lim) {
    f32x16 st[2];
    __builtin_amdgcn_s_setprio(1);
#pragma unroll
    for (int s = 0; s < 2; s++) {
#pragma unroll
        for (int e = 0; e < 16; e++) st[s][e] = 0.f;
#pragma unroll
        for (int ks = 0; ks < 4; ks++) {
            bf16x8 kf = *(const bf16x8*)(Kl + foff[s][ks]);
            st[s] = __builtin_amdgcn_mfma_f32_32x32x16_bf16(kf, qf[ks], st[s], 0, 0, 0);
        }
    }
    __builtin_amdgcn_s_setprio(0);
    if (MASKED) {
#pragma unroll
        for (int s = 0; s < 2; s++) {
            const int ls = lim - (s << 5);
#pragma unroll
            for (int r = 0; r < 16; r++) {
                const int kvloc = (r & 3) + 8 * (r >> 2);
                if (kvloc > ls) st[s][r] = -1e30f;
            }
        }
    }
    float t8[8];
#pragma unroll
    for (int r = 0; r < 8; r++)
        t8[r] = fmaxf(fmaxf(st[0][r], st[0][r + 8]),
                      fmaxf(st[1][r], st[1][r + 8]));
    float m = fmaxf(fmaxf(fmaxf(t8[0], t8[4]), fmaxf(t8[1], t8[5])),
                    fmaxf(fmaxf(t8[2], t8[6]), fmaxf(t8[3], t8[7])));
    m = fmaxf(m, __shfl_xor(m, 32));
    float mn = fmaxf(MR, m);
    if (__ballot(m - MR > 10.f)) {
        float al = fexp2(MR - mn);
        MR = mn;
        LR *= al;
#pragma unroll
        for (int e = 0; e < 16; e++) { O[0][e] *= al; O[1][e] *= al; }
    }
    float s0 = 0.f, s1 = 0.f, s2 = 0.f, s3 = 0.f;
#pragma unroll
    for (int s = 0; s < 2; s++)
#pragma unroll
        for (int r = 0; r < 16; r++) {
            float pv = fexp2(st[s][r] - MR);
            st[s][r] = pv;
            if ((r & 3) == 0) s0 += pv;
            else if ((r & 3) == 1) s1 += pv;
            else if ((r & 3) == 2) s2 += pv;
            else s3 += pv;
        }
    float sum = (s0 + s1) + (s2 + s3);
    sum += __shfl_xor(sum, 32);
    LR += sum;
#pragma unroll
    for (int ks = 0; ks < 4; ks++) {
        const int sT = ks >> 1, b1 = (ks & 1) << 3;
        u32 a = cvtpk(st[sT][b1 + 0], st[sT][b1 + 1]);
        u32 b = cvtpk(st[sT][b1 + 2], st[sT][b1 + 3]);
        u32 c = cvtpk(st[sT][b1 + 4], st[sT][b1 + 5]);
        u32 d = cvtpk(st[sT][b1 + 6], st[sT][b1 + 7]);
        permswap(a, c);
        permswap(b, d);
        bf16x8 pf = __builtin_bit_cast(bf16x8, make_uint4(a, b, c, d));
        __builtin_amdgcn_s_setprio(1);
#pragma unroll
        for (int t2 = 0; t2 < 2; t2++) {
            bf16x8 vf = *(const bf16x8*)(Vl + foff[t2][ks]);
            O[t2] = __builtin_amdgcn_mfma_f32_32x32x16_bf16(vf, pf, O[t2], 0, 0, 0);
        }
        __builtin_amdgcn_s_setprio(0);
    }
}

__global__ __launch_bounds__(256)
void attn_mfma(const u16* __restrict__ Qg, const u16* __restrict__ Kg,
               const u16* __restrict__ Vtg, u16* __restrict__ Yg) {
    __shared__ u16 Ks[2][64 * 64];
    __shared__ u16 Vts[2][64 * 64];

    const int tid = threadIdx.x;
    const int lane = tid & 63;
    const int w = tid >> 6;
    const int l31 = lane & 31, hl = lane >> 5;
    const int bh = (int)blockIdx.x;
    const int Qi = (int)gridDim.y - 1 - (int)blockIdx.y;
    const int b = bh >> 4, hd = bh & 15;
    const int qbw = (Qi << 7) + (w << 5);
    const int q_lane = qbw + l31;
    const int nst = 2 * Qi + 2;

    const u16* Qb = Qg + ((size_t)bh << 17);
    const u16* Kb = Kg + ((size_t)bh << 17);
    const u16* Vtb = Vtg + ((size_t)bh << 17);

    int foff[2][4];
#pragma unroll
    for (int s = 0; s < 2; s++)
#pragma unroll
        for (int ks = 0; ks < 4; ks++) {
            int row = (s << 5) + l31;
            foff[s][ks] = row * 128 + (((hl + (ks << 1)) ^ (row & 7)) << 4);
        }

    bf16x8 qf[4];
#pragma unroll
    for (int ks = 0; ks < 4; ks++)
        qf[ks] = *(const bf16x8*)(Qb + (((size_t)q_lane) << 6) + (hl << 3) + (ks << 4));

    f32x16 O[2];
#pragma unroll
    for (int e = 0; e < 16; e++) { O[0][e] = 0.f; O[1][e] = 0.f; }
    float MR = -1e30f, LR = 0.f;

    kv_stage2(Kb, Vtb, &Ks[0][0], &Vts[0][0], tid, 0);
    int cur = 0;

    for (int kt = 0; kt < nst; kt++) {
        if (kt + 1 < nst) {
            kv_stage2(Kb, Vtb, &Ks[cur ^ 1][0], &Vts[cur ^ 1][0], tid, (kt + 1) << 6);
            asm volatile("s_waitcnt vmcnt(4)" ::: "memory");
        } else {
            asm volatile("s_waitcnt vmcnt(0)" ::: "memory");
        }
        __builtin_amdgcn_s_barrier();
        asm volatile("" ::: "memory");
        const int kv0 = kt << 6;
        if (kv0 <= qbw + 31) {
            if (qbw - kv0 >= 63) {
                attn_step32<false>(qf, O, MR, LR, (const char*)&Ks[cur][0],
                                   (const char*)&Vts[cur][0], foff, 0);
            } else {
                int lim = q_lane - kv0 - (hl << 2);
                attn_step32<true>(qf, O, MR, LR, (const char*)&Ks[cur][0],
                                  (const char*)&Vts[cur][0], foff, lim);
            }
        }
        asm volatile("" ::: "memory");
        __builtin_amdgcn_s_barrier();
        cur ^= 1;
    }

    float inv = 1.0f / LR;
    size_t rowoff = (((size_t)(b * 2048 + q_lane)) << 10) + (hd << 6);
#pragma unroll
    for (int t2 = 0; t2 < 2; t2++)
#pragma unroll
        for (int rg = 0; rg < 4; rg++) {
            int d0 = (rg << 3) + (hl << 2) + (t2 << 5);
            u32 lo = cvtpk(O[t2][4 * rg + 0] * inv, O[t2][4 * rg + 1] * inv);
            u32 hi = cvtpk(O[t2][4 * rg + 2] * inv, O[t2][4 * rg + 3] * inv);
            *(uint2*)&Yg[rowoff + d0] = make_uint2(lo, hi);
        }
}

// ---------------------------------------------------------------------------
extern "C" void kernel_launch(void* const* d_in, const int* in_sizes, int n_in,
                              void* d_out, int out_size, void* d_ws, size_t ws_size,
                              hipStream_t stream) {
    const float* x      = (const float*)d_in[0];
    const float* w_qkv  = (const float*)d_in[1];
    const float* w_proj = (const float*)d_in[2];
    const float* b_proj = (const float*)d_in[3];
    float* out = (float*)d_out;

    const size_t SZ = (size_t)M_ROWS * CDIM;
    char* ws = (char*)d_ws;
    u16* xb     = (u16*)ws;                ws += SZ * 2;
    u16* wqkvT  = (u16*)ws;                ws += (size_t)3 * CDIM * CDIM * 2;
    u16* wprojT = (u16*)ws;                ws += (size_t)CDIM * CDIM * 2;
    u16* qkvb   = (u16*)ws;                ws += (size_t)M_ROWS * 3 * CDIM * 2;
    u16* Qb     = (u16*)ws;                ws += SZ * 2;
    u16* Kb     = (u16*)ws;                ws += SZ * 2;
    u16* Vt     = (u16*)ws;                ws += SZ * 2;
    float* cosT = (float*)ws;              ws += (size_t)T_SEQ * 32 * 4;
    float* sinT = (float*)ws;              ws += (size_t)T_SEQ * 32 * 4;
    u16* Yb = qkvb;  // alias: qkvb fully consumed before attn writes Yb

    rope_table_kernel<<<dim3(256), dim3(256), 0, stream>>>(cosT, sinT);
    conv_bf16<<<dim3(2048), dim3(256), 0, stream>>>(x, xb, (int)(SZ / 8));
    convT64<<<dim3(48, 16), dim3(256), 0, stream>>>(w_qkv, wqkvT, CDIM, 3 * CDIM);
    convT64<<<dim3(16, 16), dim3(256), 0, stream>>>(w_proj, wprojT, CDIM, CDIM);

    gemm_bf16<<<dim3(24, 32), dim3(256), 0, stream>>>(xb, wqkvT, 3 * CDIM, CDIM, qkvb);

    ropeQK<<<dim3(4096), dim3(256), 0, stream>>>(qkvb, Qb, Kb, cosT, sinT);
    transposeV2<<<dim3(32, 32), dim3(256), 0, stream>>>(qkvb, Vt);

    attn_mfma<<<dim3(32, 16), dim3(256), 0, stream>>>(Qb, Kb, Vt, Yb);

    gemm_n64<<<dim3(16, 32), dim3(256), 0, stream>>>(Yb, wprojT, CDIM, CDIM, b_proj, out);
}